// Round 3
// baseline (10678.677 us; speedup 1.0000x reference)
//
#include <hip/hip_runtime.h>

#define BATCH 128
#define SEQ   256
#define IDIM  512
#define HDIM  768
#define G4    3072
#define BK    32
#define RING  8
#define DEPTH 5
#define NBLK  192

typedef __bf16 bf16;
typedef __bf16 bf16x8 __attribute__((ext_vector_type(8)));
typedef float  f32x4  __attribute__((ext_vector_type(4)));

__device__ __forceinline__ float sigf(float x){ return 1.f/(1.f + __expf(-x)); }
__device__ __forceinline__ float tanhf_(float x){ return 1.f - 2.f/(1.f + __expf(2.f*x)); }

// direct global->LDS, 16B per lane. LDS dest = wave-uniform base + lane*16.
__device__ __forceinline__ void gll16(const bf16* g, bf16* l){
  __builtin_amdgcn_global_load_lds(
      (const __attribute__((address_space(1))) void*)g,
      (__attribute__((address_space(3))) void*)l, 16, 0, 0);
}

// ---- prep kernels -------------------------------------------------------

__global__ void convert_x_k(const float* __restrict__ x, bf16* __restrict__ xb){
  long i = ((long)blockIdx.x*256 + threadIdx.x)*8;
  float4 a = *(const float4*)(x+i);
  float4 b = *(const float4*)(x+i+4);
  bf16x8 o;
  o[0]=(bf16)a.x; o[1]=(bf16)a.y; o[2]=(bf16)a.z; o[3]=(bf16)a.w;
  o[4]=(bf16)b.x; o[5]=(bf16)b.y; o[6]=(bf16)b.z; o[7]=(bf16)b.w;
  *(bf16x8*)(xb+i) = o;
}

// Wt[c][k] (row-major, stride kc) = W[k][g*H+j], c = (j>>4)*64 + g*16 + (j&15)
__global__ void build_wt_k(const float* __restrict__ wx, const float* __restrict__ wh,
                           bf16* __restrict__ wt, int k0, int kc){
  int idx = blockIdx.x*256 + threadIdx.x;
  int c = idx / kc;
  int k = idx - c*kc;
  int g = (c >> 4) & 3;
  int j = ((c >> 6) << 4) | (c & 15);
  int oc = g*HDIM + j;
  float v = (k < k0) ? wx[(long)k*G4 + oc] : wh[(long)(k-k0)*G4 + oc];
  wt[idx] = (bf16)v;
}

__global__ void build_bias_k(const float* __restrict__ bx, const float* __restrict__ bh,
                             float* __restrict__ bc){
  int c = blockIdx.x*256 + threadIdx.x;
  int g = (c >> 4) & 3;
  int j = ((c >> 6) << 4) | (c & 15);
  int oc = g*HDIM + j;
  bc[c] = bx[oc] + bh[oc];
}

// ---- persistent recurrent kernel ---------------------------------------

struct PArgs {
  const bf16* xb;
  const bf16* wt[4];
  const float* bias[4];
  bf16* hseq[4];
  const bf16* zeros;
  float* outF; float* hnF; float* cnF;
  int* bcnt; int* bgen;
};

__device__ __forceinline__ void grid_barrier(int* cnt, int* gen, int target){
  __syncthreads();                       // all threads' stores issued
  if (threadIdx.x == 0){
    __threadfence();                     // agent-scope release: L2 writeback for cross-XCD readers
    int v = __hip_atomic_fetch_add(cnt, 1, __ATOMIC_ACQ_REL, __HIP_MEMORY_SCOPE_AGENT);
    if (v == NBLK-1){
      __hip_atomic_store(cnt, 0, __ATOMIC_RELAXED, __HIP_MEMORY_SCOPE_AGENT);
      __hip_atomic_store(gen, target, __ATOMIC_RELEASE, __HIP_MEMORY_SCOPE_AGENT);
    } else {
      // acquire on the poll load orders subsequent reads after the release-store
      while (__hip_atomic_load(gen, __ATOMIC_ACQUIRE, __HIP_MEMORY_SCOPE_AGENT) < target)
        __builtin_amdgcn_s_sleep(1);
    }
  }
  __syncthreads();                       // publish to whole block
}

__launch_bounds__(256, 1)
__global__ void lstm_persist_k(PArgs a){
  const int c = blockIdx.x / 48;          // 0=f0, 1=b0, 2=f1, 3=b1
  const int r = blockIdx.x % 48;
  const int mtile = r / 24, ntile = r % 24;
  const int tid = threadIdx.x;
  const int lane = tid & 63, wv = tid >> 6;
  const int wm = wv >> 1, wn = wv & 1;
  const int l15 = lane & 15, q = lane >> 4;

  const int k0 = (c < 2) ? IDIM : HDIM;
  const int kc = (c < 2) ? (IDIM + HDIM) : (2*HDIM);
  const int nk = kc / BK;                 // 40 or 48

  __shared__ __align__(16) bf16 sA[RING][64*BK];    // 32 KB
  __shared__ __align__(16) bf16 sB[RING][128*BK];   // 64 KB

  // staging geometry: each 1024B LDS region = 16 rows x 32 bf16.
  // XOR chunk swizzle baked into the per-lane GLOBAL source address.
  const int rl  = lane >> 2;
  const int lch = (lane & 3) ^ ((lane >> 3) & 3);
  const int ra  = wv*16 + rl;
  const int ga  = mtile*64 + ra;

  const long ncol0 = (long)ntile*128;
  const bf16* wtc = a.wt[c];
  const bf16* b0p = wtc + (ncol0 + wv*16     + rl) * (long)kc + lch*8;
  const bf16* b1p = wtc + (ncol0 + (wv+4)*16 + rl) * (long)kc + lch*8;

  bf16* sAw  = &sA[0][0] + wv*512;
  bf16* sBw0 = &sB[0][0] + wv*512;
  bf16* sBw1 = &sB[0][0] + (wv+4)*512;

  const int psel = (q ^ ((l15 >> 1) & 3)) * 8;   // swizzled chunk for frag reads

  // epilogue constants (fixed for this block, all 256 steps)
  const int colb = ntile*128 + wn*64;
  const int j = ((colb >> 6) << 4) | l15;
  float bias4[4];
#pragma unroll
  for (int ni=0; ni<4; ++ni) bias4[ni] = a.bias[c][colb + ni*16 + l15];
  const int hni = (c==0) ? 0 : (c==1) ? 2 : (c==2) ? 1 : 3;  // h_n stack order
  const size_t BH = (size_t)BATCH*HDIM;
  bf16* hseqc = a.hseq[c];

  float creg[2][4] = {{0.f,0.f,0.f,0.f},{0.f,0.f,0.f,0.f}};  // cell state in regs

  for (int kk = 0; kk <= SEQ; ++kk){
    int active, t;
    const bf16* seg0; long s0stride;
    if (c < 2){                                 // layer 0 at t = kk
      active = (kk < SEQ); t = active ? kk : 0;
      int ts = (c==0) ? t : (SEQ-1-t);
      seg0 = a.xb + (size_t)ts*IDIM; s0stride = (long)SEQ*IDIM;
    } else {                                    // layer 1 at t = kk-1
      active = (kk >= 1); t = active ? (kk-1) : 0;
      seg0 = a.hseq[c-2] + (size_t)t*BH; s0stride = HDIM;
    }

    if (active){
      const bf16* seg1 = (t==0) ? a.zeros : (hseqc + (size_t)(t-1)*BH);
      const bf16* a0 = seg0 + (long)ga * s0stride + lch*8;
      const bf16* a1 = seg1 + (long)ga * HDIM + lch*8 - k0;

      f32x4 acc[2][4] = {};

      // prologue: stage batches 0..DEPTH-1 into ring slots 0..DEPTH-1
#pragma unroll
      for (int pb = 0; pb < DEPTH; ++pb){
        const bf16* as = (pb*BK < k0) ? (a0 + pb*BK) : (a1 + pb*BK);
        gll16(as,          sAw  + pb*(64*BK));
        gll16(b0p + pb*BK, sBw0 + pb*(128*BK));
        gll16(b1p + pb*BK, sBw1 + pb*(128*BK));
      }

      for (int kb = 0; kb < nk; ++kb){
        int w_ = nk-1-kb;                        // batches still to consume after this
        if (w_ >= 4)      asm volatile("s_waitcnt vmcnt(12)" ::: "memory");
        else if (w_ == 3) asm volatile("s_waitcnt vmcnt(9)"  ::: "memory");
        else if (w_ == 2) asm volatile("s_waitcnt vmcnt(6)"  ::: "memory");
        else if (w_ == 1) asm volatile("s_waitcnt vmcnt(3)"  ::: "memory");
        else              asm volatile("s_waitcnt vmcnt(0)"  ::: "memory");
        __builtin_amdgcn_s_barrier();            // publish batch kb; guard slot reuse
        __builtin_amdgcn_sched_barrier(0);

        int nb = kb + DEPTH;
        if (nb < nk){
          int buf = nb & (RING-1);
          const bf16* as = (nb*BK < k0) ? (a0 + nb*BK) : (a1 + nb*BK);
          gll16(as,          sAw  + buf*(64*BK));
          gll16(b0p + nb*BK, sBw0 + buf*(128*BK));
          gll16(b1p + nb*BK, sBw1 + buf*(128*BK));
        }

        const bf16* A  = sA[kb & (RING-1)];
        const bf16* Bm = sB[kb & (RING-1)];
        bf16x8 af[2], bfr[4];
#pragma unroll
        for (int mi = 0; mi < 2; ++mi)
          af[mi] = *(const bf16x8*)(A + (wm*32 + mi*16 + l15)*BK + psel);
#pragma unroll
        for (int ni = 0; ni < 4; ++ni)
          bfr[ni] = *(const bf16x8*)(Bm + (wn*64 + ni*16 + l15)*BK + psel);
#pragma unroll
        for (int mi = 0; mi < 2; ++mi)
#pragma unroll
          for (int ni = 0; ni < 4; ++ni)
            acc[mi][ni] = __builtin_amdgcn_mfma_f32_16x16x32_bf16(af[mi], bfr[ni], acc[mi][ni], 0, 0, 0);
        __builtin_amdgcn_sched_barrier(0);
      }

      // epilogue: lane holds gates f,i,g,o (ni 0..3) of hidden unit j, 8 batch rows
      float* op = nullptr;
      if (c >= 2)
        op = (c==2) ? (a.outF + (size_t)t*2*HDIM)
                    : (a.outF + (size_t)(SEQ-1-t)*2*HDIM + HDIM);
      bf16* hrow = hseqc + (size_t)t*BH;
      const int last = (t == SEQ-1);

#pragma unroll
      for (int mi=0; mi<2; ++mi){
        int b0 = mtile*64 + wm*32 + mi*16 + q*4;
#pragma unroll
        for (int rg=0; rg<4; ++rg){
          int b = b0 + rg;
          float fg = acc[mi][0][rg] + bias4[0];
          float ig = acc[mi][1][rg] + bias4[1];
          float gg = acc[mi][2][rg] + bias4[2];
          float og = acc[mi][3][rg] + bias4[3];
          float co = creg[mi][rg];
          float cn = sigf(fg)*co + sigf(ig)*tanhf_(gg);
          float h  = sigf(og)*tanhf_(cn);
          creg[mi][rg] = cn;
          hrow[b*HDIM + j] = (bf16)h;
          if (op) op[(long)b*(SEQ*2*HDIM) + j] = h;
          if (last){
            a.hnF[hni*BH + b*HDIM + j] = h;
            a.cnF[hni*BH + b*HDIM + j] = cn;
          }
        }
      }
    }

    if (kk < SEQ) grid_barrier(a.bcnt, a.bgen, kk+1);
  }
}

// ---- host ---------------------------------------------------------------

extern "C" void kernel_launch(void* const* d_in, const int* in_sizes, int n_in,
                              void* d_out, int out_size, void* d_ws, size_t ws_size,
                              hipStream_t stream){
  (void)in_sizes; (void)n_in; (void)out_size; (void)ws_size;
  const float* x = (const float*)d_in[0];
  const float* Wx[4]; const float* bxp[4]; const float* Whp[4]; const float* bhp[4];
  for (int t=0; t<4; ++t){                   // input tag order: f0, f1, b0, b1
    Wx[t]  = (const float*)d_in[1 + 4*t];
    bxp[t] = (const float*)d_in[2 + 4*t];
    Whp[t] = (const float*)d_in[3 + 4*t];
    bhp[t] = (const float*)d_in[4 + 4*t];
  }
  // cell order: 0=f0, 1=b0, 2=f1, 3=b1
  const int tag[4] = {0, 2, 1, 3};
  const int k0c[4] = {IDIM, IDIM, HDIM, HDIM};
  const int kcc[4] = {IDIM+HDIM, IDIM+HDIM, 2*HDIM, 2*HDIM};

  char* ws = (char*)d_ws;
  size_t off = 0;
  auto take = [&](size_t bytes)->char*{ char* pp = ws + off; off += (bytes + 255) & ~(size_t)255; return pp; };

  bf16* xb = (bf16*)take((size_t)BATCH*SEQ*IDIM*2);
  bf16* wt[4];    for (int c=0;c<4;++c) wt[c]   = (bf16*)take((size_t)G4*kcc[c]*2);
  float* bias[4]; for (int c=0;c<4;++c) bias[c] = (float*)take((size_t)G4*4);
  bf16* hseq[4];  for (int c=0;c<4;++c) hseq[c] = (bf16*)take((size_t)SEQ*BATCH*HDIM*2);
  bf16* zeros = (bf16*)take((size_t)BATCH*HDIM*2);
  int*  barp  = (int*)take(512);             // [cnt @ +0, gen @ +256B], zeroed below

  // zeros + barrier region are contiguous -> one memset
  size_t zlen = (size_t)BATCH*HDIM*2 + 512;
  (void)hipMemsetAsync(zeros, 0, zlen, stream);

  convert_x_k<<<dim3((BATCH*SEQ*IDIM)/(8*256)), dim3(256), 0, stream>>>(x, xb);
  for (int c=0;c<4;++c)
    build_wt_k<<<dim3((G4*kcc[c])/256), dim3(256), 0, stream>>>(Wx[tag[c]], Whp[tag[c]], wt[c], k0c[c], kcc[c]);
  for (int c=0;c<4;++c)
    build_bias_k<<<dim3(G4/256), dim3(256), 0, stream>>>(bxp[tag[c]], bhp[tag[c]], bias[c]);

  float* outF = (float*)d_out;
  float* hnF  = outF + (size_t)BATCH*SEQ*2*HDIM;
  float* cnF  = hnF + (size_t)4*BATCH*HDIM;

  PArgs A;
  A.xb = xb;
  for (int c=0;c<4;++c){ A.wt[c] = wt[c]; A.bias[c] = bias[c]; A.hseq[c] = hseq[c]; }
  A.zeros = zeros;
  A.outF = outF; A.hnF = hnF; A.cnF = cnF;
  A.bcnt = barp; A.bgen = barp + 64;          // +256 bytes

  lstm_persist_k<<<dim3(NBLK), dim3(256), 0, stream>>>(A);
}